// Round 7
// baseline (253.085 us; speedup 1.0000x reference)
//
#include <hip/hip_runtime.h>

typedef _Float16 f16;
typedef _Float16 f16x4 __attribute__((ext_vector_type(4)));
typedef _Float16 f16x8 __attribute__((ext_vector_type(8)));
typedef float f32x4 __attribute__((ext_vector_type(4)));

#define AS1 __attribute__((address_space(1)))
#define AS3 __attribute__((address_space(3)))

__device__ __forceinline__ void gl_lds16(const f16* g, f16* l) {
  __builtin_amdgcn_global_load_lds((const AS1 void*)g, (AS3 void*)l, 16, 0, 0);
}

// ---------------- LayerNorm: x (fp32) -> H (f16), one WAVE per row ----------------
__global__ __launch_bounds__(256) void ln_kernel(const float* __restrict__ x,
                                                 const float* __restrict__ gw,
                                                 const float* __restrict__ gb,
                                                 f16* __restrict__ H) {
  const int wv = threadIdx.x >> 6, lane = threadIdx.x & 63;
  const long row = (long)blockIdx.x * 4 + wv;
  const float* xr = x + row * 1024;
  float4 v[4];
  float s = 0.f, s2 = 0.f;
#pragma unroll
  for (int j = 0; j < 4; ++j) {
    v[j] = ((const float4*)xr)[lane + 64 * j];
    s  += v[j].x + v[j].y + v[j].z + v[j].w;
    s2 += v[j].x * v[j].x + v[j].y * v[j].y + v[j].z * v[j].z + v[j].w * v[j].w;
  }
#pragma unroll
  for (int off = 32; off > 0; off >>= 1) {
    s  += __shfl_xor(s, off);
    s2 += __shfl_xor(s2, off);
  }
  const float mu = s * (1.0f / 1024.0f);
  const float rstd = rsqrtf(s2 * (1.0f / 1024.0f) - mu * mu + 1e-5f);
#pragma unroll
  for (int j = 0; j < 4; ++j) {
    const float4 w4 = ((const float4*)gw)[lane + 64 * j];
    const float4 b4 = ((const float4*)gb)[lane + 64 * j];
    f16x4 h;
    h[0] = (f16)((v[j].x - mu) * rstd * w4.x + b4.x);
    h[1] = (f16)((v[j].y - mu) * rstd * w4.y + b4.y);
    h[2] = (f16)((v[j].z - mu) * rstd * w4.z + b4.z);
    h[3] = (f16)((v[j].w - mu) * rstd * w4.w + b4.w);
    *(f16x4*)(H + row * 1024 + (lane + 64 * j) * 4) = h;
  }
}

// ---------------- transpose H (b,t,c) -> Ht (b,c,t), 64x64 tiles, fused colsum ----------------
__global__ __launch_bounds__(256) void transpose_cs_kernel(const f16* __restrict__ H,
                                                           f16* __restrict__ Ht,
                                                           float* __restrict__ hs) {
  __shared__ f16 tile[64][68];
  __shared__ float csum[4][64];
  const int b = blockIdx.z;
  const long Hb  = (long)b * 4096 * 1024;
  const long Htb = (long)b * 1024 * 4096;
  const int t0 = blockIdx.y * 64, c0 = blockIdx.x * 64;
  const int tid = threadIdx.x;
  const int r = tid >> 2, g0 = tid & 3;
#pragma unroll
  for (int i = 0; i < 4; ++i) {
    const int g = g0 + i * 4;
    f16x4 v = *(const f16x4*)(H + Hb + (long)(t0 + r) * 1024 + c0 + g * 4);
    *(f16x4*)&tile[r][g * 4] = v;
  }
  __syncthreads();
  {
    const int cl = tid & 63, rg = tid >> 6;
    float s = 0.f;
#pragma unroll
    for (int rr = 0; rr < 16; ++rr) s += (float)tile[rg * 16 + rr][cl];
    csum[rg][cl] = s;
  }
#pragma unroll
  for (int i = 0; i < 4; ++i) {
    const int g = g0 + i * 4;
    f16x4 v;
    v[0] = tile[g * 4 + 0][r];
    v[1] = tile[g * 4 + 1][r];
    v[2] = tile[g * 4 + 2][r];
    v[3] = tile[g * 4 + 3][r];
    *(f16x4*)(Ht + Htb + (long)(c0 + r) * 4096 + t0 + g * 4) = v;
  }
  __syncthreads();
  if (tid < 64)
    atomicAdd(&hs[b * 1024 + c0 + tid],
              csum[0][tid] + csum[1][tid] + csum[2][tid] + csum[3][tid]);
}

// ---------------- cast fp32 -> f16, two ranges in one dispatch ----------------
__global__ __launch_bounds__(256) void cast2_f32_f16(const float* __restrict__ s1,
                                                     f16* __restrict__ d1, int n4_1,
                                                     const float* __restrict__ s2,
                                                     f16* __restrict__ d2, int n4_2) {
  int i = blockIdx.x * 256 + threadIdx.x;
  const float* src; f16* dst;
  if (i < n4_1) { src = s1; dst = d1; }
  else { i -= n4_1; if (i >= n4_2) return; src = s2; dst = d2; }
  float4 v = ((const float4*)src)[i];
  f16x4 h;
  h[0] = (f16)v.x; h[1] = (f16)v.y; h[2] = (f16)v.z; h[3] = (f16)v.w;
  ((f16x4*)dst)[i] = h;
}

// ---------------- transpose+cast Wq: WqT[d][i] = Wq[i][d] ----------------
__global__ __launch_bounds__(256) void transcast_kernel(const float* __restrict__ W,
                                                        f16* __restrict__ WT) {
  __shared__ f16 tile[64][68];
  const int r0 = blockIdx.y * 64, c0 = blockIdx.x * 64;
  const int tid = threadIdx.x;
  const int r = tid >> 2, g0 = tid & 3;
#pragma unroll
  for (int i = 0; i < 4; ++i) {
    const int g = g0 + i * 4;
    float4 v = *(const float4*)(W + (long)(r0 + r) * 1024 + c0 + g * 4);
    tile[r][g * 4 + 0] = (f16)v.x;
    tile[r][g * 4 + 1] = (f16)v.y;
    tile[r][g * 4 + 2] = (f16)v.z;
    tile[r][g * 4 + 3] = (f16)v.w;
  }
  __syncthreads();
#pragma unroll
  for (int i = 0; i < 4; ++i) {
    const int g = g0 + i * 4;
    f16x4 v;
    v[0] = tile[g * 4 + 0][r];
    v[1] = tile[g * 4 + 1][r];
    v[2] = tile[g * 4 + 2][r];
    v[3] = tile[g * 4 + 3][r];
    *(f16x4*)(WT + (long)(c0 + r) * 1024 + r0 + g * 4) = v;
  }
}

// ---------------- u[b] = Wk hs_b, w[b] = Wv hs_b (f16 weights, one wave per output) ----------------
__global__ void gemv_uw(const f16* __restrict__ Wh, const float* __restrict__ hs,
                        float* __restrict__ uvec, float* __restrict__ wvec) {
  const int bid = blockIdx.x;
  const int b = bid >> 11;
  const int rem = bid & 2047;
  const int which = rem >> 10;
  const int i = rem & 1023;
  const f16* row = Wh + (long)(1024 + which * 1024 + i) * 1024;
  const float* h = hs + b * 1024;
  const int lane = threadIdx.x;
  float s = 0.f;
#pragma unroll
  for (int j = 0; j < 2; ++j) {
    const int d = (lane + 64 * j) * 8;
    f16x8 a = *(const f16x8*)(row + d);
    float4 h0 = *(const float4*)(h + d);
    float4 h1 = *(const float4*)(h + d + 4);
    s += (float)a[0] * h0.x + (float)a[1] * h0.y + (float)a[2] * h0.z + (float)a[3] * h0.w
       + (float)a[4] * h1.x + (float)a[5] * h1.y + (float)a[6] * h1.z + (float)a[7] * h1.w;
  }
#pragma unroll
  for (int off = 32; off > 0; off >>= 1) s += __shfl_down(s, off);
  if (lane == 0) { (which ? wvec : uvec)[b * 1024 + i] = s; }
}

// ---------------- c2[b][c] = sum_i R[b][c][i]*bq[i] + proj_b[c] ----------------
__global__ void c2_kernel(const f16* __restrict__ R, const float* __restrict__ qkv_b,
                          const float* __restrict__ proj_b, float* __restrict__ c2) {
  const int bid = blockIdx.x;
  const int b = bid >> 10, c = bid & 1023;
  const f16* row = R + (long)b * 1048576 + (long)c * 1024;
  const int lane = threadIdx.x;
  float s = 0.f;
#pragma unroll
  for (int j = 0; j < 4; ++j) {
    const int i0 = (lane + 64 * j) * 4;
    f16x4 rv = *(const f16x4*)(row + i0);
    float4 q = *(const float4*)(qkv_b + i0);
    s += (float)rv[0] * q.x + (float)rv[1] * q.y + (float)rv[2] * q.z + (float)rv[3] * q.w;
  }
#pragma unroll
  for (int off = 32; off > 0; off >>= 1) s += __shfl_down(s, off);
  if (lane == 0) c2[b * 1024 + c] = s + proj_b[c];
}

// ================= shared GEMM machinery =================
#define GEMM_PROLOGUE_SWZ()                                       \
  const int tid = threadIdx.x;                                    \
  const int wave = tid >> 6, lane = tid & 63;                     \
  const int wm = wave >> 1, wn = wave & 1;                        \
  const int lr = lane & 15, lk = lane >> 4;                       \
  const int W0 = tid * 16;                                        \
  const int L0 = W0 ^ (((W0 >> 7) & 3) << 4);                     \
  const int r0 = L0 >> 6, g0 = (L0 >> 4) & 3;                     \
  const int W1 = W0 + 4096;                                       \
  const int L1 = W1 ^ (((W1 >> 7) & 3) << 4);                     \
  const int r1 = L1 >> 6, g1 = (L1 >> 4) & 3;                     \
  const int kk8 = (lk ^ ((lr >> 1) & 3)) * 8;

#define GEMM_COMPUTE(asb_, bsb_)                                                 \
  do {                                                                           \
    const f16* asb = (asb_);                                                     \
    const f16* bsb = (bsb_);                                                     \
    f16x8 af[4], bf[4];                                                          \
    _Pragma("unroll")                                                            \
    for (int mi = 0; mi < 4; ++mi)                                               \
      af[mi] = *(const f16x8*)(asb + (wm * 64 + mi * 16 + lr) * 32 + kk8);       \
    _Pragma("unroll")                                                            \
    for (int ni = 0; ni < 4; ++ni)                                               \
      bf[ni] = *(const f16x8*)(bsb + (wn * 64 + ni * 16 + lr) * 32 + kk8);       \
    _Pragma("unroll")                                                            \
    for (int mi = 0; mi < 4; ++mi)                                               \
      _Pragma("unroll")                                                          \
      for (int ni = 0; ni < 4; ++ni)                                             \
        acc[mi][ni] = __builtin_amdgcn_mfma_f32_16x16x32_f16(af[mi], bf[ni],     \
                                                             acc[mi][ni], 0, 0, 0); \
  } while (0)

#define GEMM_WAIT(NBUF_, r_)                                             \
  do {                                                                   \
    if constexpr (NBUF_ == 4) {                                          \
      if ((r_) >= 3)      asm volatile("s_waitcnt vmcnt(12)" ::: "memory"); \
      else if ((r_) == 2) asm volatile("s_waitcnt vmcnt(8)" ::: "memory");  \
      else if ((r_) == 1) asm volatile("s_waitcnt vmcnt(4)" ::: "memory");  \
      else                asm volatile("s_waitcnt vmcnt(0)" ::: "memory");  \
    } else if constexpr (NBUF_ == 3) {                                   \
      if ((r_) >= 2)      asm volatile("s_waitcnt vmcnt(8)" ::: "memory");  \
      else if ((r_) == 1) asm volatile("s_waitcnt vmcnt(4)" ::: "memory");  \
      else                asm volatile("s_waitcnt vmcnt(0)" ::: "memory");  \
    } else {                                                             \
      if ((r_) >= 1)      asm volatile("s_waitcnt vmcnt(4)" ::: "memory");  \
      else                asm volatile("s_waitcnt vmcnt(0)" ::: "memory");  \
    }                                                                    \
  } while (0)

// ---------------- chain GEMM: 128x128 tile, split-K=2, f16 partials ----------------
// z = ks*4 + b; K slice [ks*512, ks*512+512). part[z][m][n] = sum_k A[m,k]B[n,k]
__global__ __launch_bounds__(256) void gemm128s(
    const f16* __restrict__ A, const f16* __restrict__ B,
    long sA, long sB, f16* __restrict__ part) {
  const int z = blockIdx.z;
  const int b = z & 3;
  const long kbase = (long)(z >> 2) * 512;
  A += (long)b * sA;
  B += (long)b * sB;
  const int nx = blockIdx.y;   // XCD-style transposed mapping (lin%8 == ny)
  const int ny = blockIdx.x;

  GEMM_PROLOGUE_SWZ();

  __shared__ __align__(16) f16 As[3][4096];
  __shared__ __align__(16) f16 Bs[3][4096];

  const long aoff0 = (long)(ny * 128 + r0) * 1024 + kbase + g0 * 8;
  const long aoff1 = (long)(ny * 128 + r1) * 1024 + kbase + g1 * 8;
  const long boff0 = (long)(nx * 128 + r0) * 1024 + kbase + g0 * 8;
  const long boff1 = (long)(nx * 128 + r1) * 1024 + kbase + g1 * 8;

  f32x4 zero = {0.f, 0.f, 0.f, 0.f};
  f32x4 acc[4][4];
#pragma unroll
  for (int mi = 0; mi < 4; ++mi)
#pragma unroll
    for (int ni = 0; ni < 4; ++ni) acc[mi][ni] = zero;

#define STAGE(buf, k0)                                  \
  do {                                                  \
    f16* asb = &As[buf][0];                             \
    f16* bsb = &Bs[buf][0];                             \
    gl_lds16(A + aoff0 + (k0), asb + tid * 8);          \
    gl_lds16(A + aoff1 + (k0), asb + tid * 8 + 2048);   \
    gl_lds16(B + boff0 + (k0), bsb + tid * 8);          \
    gl_lds16(B + boff1 + (k0), bsb + tid * 8 + 2048);   \
  } while (0)

  const int nt = 16;
  STAGE(0, 0);
  STAGE(1, 32);
  int cur = 0, stg = 2;
  for (int t = 0; t < nt; ++t) {
    if (t + 2 < nt) STAGE(stg, (t + 2) << 5);
    GEMM_WAIT(3, nt - 1 - t);
    asm volatile("s_barrier" ::: "memory");
    GEMM_COMPUTE(&As[cur][0], &Bs[cur][0]);
    asm volatile("s_waitcnt lgkmcnt(0)" ::: "memory");
    asm volatile("s_barrier" ::: "memory");
    cur = (cur + 1 == 3) ? 0 : cur + 1;
    stg = (stg + 1 == 3) ? 0 : stg + 1;
  }
#undef STAGE

  f16* P = part + (long)z * 1048576;
  const int m0 = ny * 128 + wm * 64;
  const int n0 = nx * 128 + wn * 64;
#pragma unroll
  for (int mi = 0; mi < 4; ++mi)
#pragma unroll
    for (int ni = 0; ni < 4; ++ni)
#pragma unroll
      for (int j = 0; j < 4; ++j) {
        const int gm = m0 + mi * 16 + lk * 4 + j;
        const int gn = n0 + ni * 16 + lr;
        P[(long)gm * 1024 + gn] = (f16)acc[mi][ni][j];
      }
}

// ---------------- reduce split-K=2 chain partials; RANK1 adds bias terms + /32 ----------------
template <int RANK1>
__global__ __launch_bounds__(256) void reduce2(const f16* __restrict__ part,
                                               f16* __restrict__ Ch,
                                               const float* __restrict__ uvec,
                                               const float* __restrict__ wvec,
                                               const float* __restrict__ bkv,
                                               const float* __restrict__ bvv) {
  const int b = blockIdx.y;
  const int tid = threadIdx.x;
  const int n = tid * 4;
  const f16* P1 = part + (long)b * 1048576;
  const f16* P2 = part + (long)(b + 4) * 1048576;
  float4 ww, bvn;
  if constexpr (RANK1) {
    ww  = *(const float4*)&wvec[b * 1024 + n];
    bvn = *(const float4*)&bvv[n];
  }
#pragma unroll
  for (int it = 0; it < 4; ++it) {
    const int m = blockIdx.x * 4 + it;
    const long e = (long)m * 1024 + n;
    f16x4 p0 = *(const f16x4*)(P1 + e);
    f16x4 p1 = *(const f16x4*)(P2 + e);
    f16x4 r;
    if constexpr (RANK1) {
      const float uu = uvec[b * 1024 + m];
      const float bkm = bkv[m];
      r[0] = (f16)(((float)p0[0] + (float)p1[0] + uu * bvn.x + bkm * ww.x + 4096.f * bkm * bvn.x) * 0.03125f);
      r[1] = (f16)(((float)p0[1] + (float)p1[1] + uu * bvn.y + bkm * ww.y + 4096.f * bkm * bvn.y) * 0.03125f);
      r[2] = (f16)(((float)p0[2] + (float)p1[2] + uu * bvn.z + bkm * ww.z + 4096.f * bkm * bvn.z) * 0.03125f);
      r[3] = (f16)(((float)p0[3] + (float)p1[3] + uu * bvn.w + bkm * ww.w + 4096.f * bkm * bvn.w) * 0.03125f);
    } else {
#pragma unroll
      for (int j = 0; j < 4; ++j)
        r[j] = (f16)((float)p0[j] + (float)p1[j]);
    }
    *(f16x4*)(Ch + (long)b * 1048576 + e) = r;
  }
}

// ---------------- FINAL GEMM: 256x256 tile, 8 waves, LDS-vectorized fp32 epilogue ----------------
__global__ __launch_bounds__(512) void gemm256f(
    const f16* __restrict__ A,       // H flat [16384][1024]
    const f16* __restrict__ Bw,      // W2T [4][1024][1024]
    const float* __restrict__ resid,
    const float* __restrict__ c2v,
    float* __restrict__ outF) {
  const int lin = blockIdx.y * 4 + blockIdx.x;   // 0..255
  const int xcd = lin & 7, slot = lin >> 3;
  const int ny = xcd * 8 + (slot >> 2);          // 0..63  (M tile)
  const int nx = slot & 3;                       // 0..3   (N tile)
  const int bb = ny >> 4;

  const int tid = threadIdx.x;
  const int wave = tid >> 6, lane = tid & 63;
  const int wm = wave >> 2, wn = wave & 3;
  const int lr = lane & 15, lk = lane >> 4;

  __shared__ __align__(16) f16 As[3][8192];
  __shared__ __align__(16) f16 Bs[3][8192];

  const int W0 = tid * 16;
  const int L0 = W0 ^ (((W0 >> 7) & 3) << 4);
  const int r0 = L0 >> 6, g0 = (L0 >> 4) & 3;
  const int W1 = W0 + 8192;
  const int L1 = W1 ^ (((W1 >> 7) & 3) << 4);
  const int r1 = L1 >> 6, g1 = (L1 >> 4) & 3;
  const int kk8 = (lk ^ ((lr >> 1) & 3)) * 8;

  const f16* Ab = A + (long)ny * 262144;
  const f16* Bb = Bw + (long)bb * 1048576 + (long)nx * 262144;
  const long aoff0 = (long)r0 * 1024 + g0 * 8;
  const long aoff1 = (long)r1 * 1024 + g1 * 8;
  const long boff0 = aoff0, boff1 = aoff1;

  f32x4 zero = {0.f, 0.f, 0.f, 0.f};
  f32x4 acc[8][4];
#pragma unroll
  for (int mi = 0; mi < 8; ++mi)
#pragma unroll
    for (int ni = 0; ni < 4; ++ni) acc[mi][ni] = zero;

#define STAGE(buf, k0)                                  \
  do {                                                  \
    f16* asb = &As[buf][0];                             \
    f16* bsb = &Bs[buf][0];                             \
    gl_lds16(Ab + aoff0 + (k0), asb + tid * 8);         \
    gl_lds16(Ab + aoff1 + (k0), asb + tid * 8 + 4096);  \
    gl_lds16(Bb + boff0 + (k0), bsb + tid * 8);         \
    gl_lds16(Bb + boff1 + (k0), bsb + tid * 8 + 4096);  \
  } while (0)

  const int nt = 32;
  STAGE(0, 0);
  STAGE(1, 32);
  int cur = 0, stg = 2;
  for (int t = 0; t < nt; ++t) {
    if (t + 2 < nt) STAGE(stg, (t + 2) << 5);
    GEMM_WAIT(3, nt - 1 - t);
    asm volatile("s_barrier" ::: "memory");
    {
      const f16* asb = &As[cur][0];
      const f16* bsb = &Bs[cur][0];
      f16x8 af[8], bf[4];
#pragma unroll
      for (int mi = 0; mi < 8; ++mi)
        af[mi] = *(const f16x8*)(asb + (wm * 128 + mi * 16 + lr) * 32 + kk8);
#pragma unroll
      for (int ni = 0; ni < 4; ++ni)
        bf[ni] = *(const f16x8*)(bsb + (wn * 64 + ni * 16 + lr) * 32 + kk8);
#pragma unroll
      for (int mi = 0; mi < 8; ++mi)
#pragma unroll
        for (int ni = 0; ni < 4; ++ni)
          acc[mi][ni] = __builtin_amdgcn_mfma_f32_16x16x32_f16(af[mi], bf[ni],
                                                               acc[mi][ni], 0, 0, 0);
    }
    asm volatile("s_waitcnt lgkmcnt(0)" ::: "memory");
    asm volatile("s_barrier" ::: "memory");
    cur = (cur + 1 == 3) ? 0 : cur + 1;
    stg = (stg + 1 == 3) ? 0 : stg + 1;
  }
#undef STAGE

  // -------- LDS-staged vectorized epilogue --------
  // All waves passed the final barrier: As is free. Wave-private 16x68 f32 region.
  float* weps = ((float*)&As[0][0]) + wave * 1088;   // 1088*4 = 4352 B per wave
  const int m0 = ny * 256 + wm * 128;
  const int n0 = nx * 256 + wn * 64;
  const int err = lane >> 3;          // 0..7 (row within 8-row group)
  const int ecc = (lane & 7) * 4;     // 0..28 (col chunk)
  float4 cc2[2];
#pragma unroll
  for (int q = 0; q < 2; ++q)
    cc2[q] = *(const float4*)&c2v[bb * 1024 + n0 + ecc + 32 * q];

#pragma unroll
  for (int mi = 0; mi < 8; ++mi) {
#pragma unroll
    for (int ni = 0; ni < 4; ++ni)
#pragma unroll
      for (int j = 0; j < 4; ++j)
        weps[(lk * 4 + j) * 68 + ni * 16 + lr] = acc[mi][ni][j];
    asm volatile("s_waitcnt lgkmcnt(0)" ::: "memory");
#pragma unroll
    for (int h = 0; h < 2; ++h)
#pragma unroll
      for (int q = 0; q < 2; ++q) {
        const int rr = err + 8 * h;
        const int cc = ecc + 32 * q;
        float4 o = *(const float4*)&weps[rr * 68 + cc];
        const long gbase = (long)(m0 + mi * 16 + rr) * 1024 + n0 + cc;
        const float4 rv = *(const float4*)&resid[gbase];
        float4 ov;
        ov.x = o.x + rv.x + cc2[q].x;
        ov.y = o.y + rv.y + cc2[q].y;
        ov.z = o.z + rv.z + cc2[q].z;
        ov.w = o.w + rv.w + cc2[q].w;
        *(float4*)&outF[gbase] = ov;
      }
  }
}

// ---------------- G = H^T H, upper-triangle tiles only, split-K=4, f16 partials ----------------
__global__ __launch_bounds__(256) void gemmGt(const f16* __restrict__ Ht,
                                              f16* __restrict__ part) {
  const int z = blockIdx.z;
  const int b = z & 3, ks = z >> 2;
  int ti = 0, trem = blockIdx.x;
  while (trem >= 8 - ti) { trem -= 8 - ti; ++ti; }
  const int tj = ti + trem;
  const f16* Hb = Ht + (long)b * 4194304;

  GEMM_PROLOGUE_SWZ();

  __shared__ __align__(16) f16 As[4][4096];
  __shared__ __align__(16) f16 Bs[4][4096];

  const long kbase = (long)ks * 1024;
  const long aoff0 = (long)(ti * 128 + r0) * 4096 + kbase + g0 * 8;
  const long aoff1 = (long)(ti * 128 + r1) * 4096 + kbase + g1 * 8;
  const long boff0 = (long)(tj * 128 + r0) * 4096 + kbase + g0 * 8;
  const long boff1 = (long)(tj * 128 + r1) * 4096 + kbase + g1 * 8;

  f32x4 zero = {0.f, 0.f, 0.f, 0.f};
  f32x4 acc[4][4];
#pragma unroll
  for (int mi = 0; mi < 4; ++mi)
#pragma unroll
    for (int ni = 0; ni < 4; ++ni) acc[mi][ni] = zero;

#define STAGE(buf, k0)                                   \
  do {                                                   \
    f16* asb = &As[buf][0];                              \
    f16* bsb = &Bs[buf][0];                              \
    gl_lds16(Hb + aoff0 + (k0), asb + tid * 8);          \
    gl_lds16(Hb + aoff1 + (k0), asb + tid * 8 + 2048);   \
    gl_lds16(Hb + boff0 + (k0), bsb + tid * 8);          \
    gl_lds16(Hb + boff1 + (k0), bsb + tid * 8 + 2048);   \
  } while (0)

  const int nt = 32;
#pragma unroll
  for (int i = 0; i < 3; ++i) STAGE(i, i << 5);

  int cur = 0, stg = 3;
  for (int t = 0; t < nt; ++t) {
    if (t + 3 < nt) STAGE(stg, (t + 3) << 5);
    GEMM_WAIT(4, nt - 1 - t);
    asm volatile("s_barrier" ::: "memory");
    GEMM_COMPUTE(&As[cur][0], &Bs[cur][0]);
    asm volatile("s_waitcnt lgkmcnt(0)" ::: "memory");
    asm volatile("s_barrier" ::: "memory");
    cur = (cur + 1 == 4) ? 0 : cur + 1;
    stg = (stg + 1 == 4) ? 0 : stg + 1;
  }
#undef STAGE

  f16* P = part + ((long)z * 36 + blockIdx.x) * 16384;
#pragma unroll
  for (int mi = 0; mi < 4; ++mi)
#pragma unroll
    for (int ni = 0; ni < 4; ++ni)
#pragma unroll
      for (int j = 0; j < 4; ++j) {
        const int gm = wm * 64 + mi * 16 + lk * 4 + j;
        const int gn = wn * 64 + ni * 16 + lr;
        P[gm * 128 + gn] = (f16)acc[mi][ni][j];
      }
}

// ---------------- reduce 4 K-slices of triangular G partials -> Gh, mirror off-diag ----------------
__global__ __launch_bounds__(256) void treduce(const f16* __restrict__ part,
                                               f16* __restrict__ Gh) {
  const int tileid = blockIdx.x, b = blockIdx.y;
  int ti = 0, trem = tileid;
  while (trem >= 8 - ti) { trem -= 8 - ti; ++ti; }
  const int tj = ti + trem;
  __shared__ f16 tl[128][132];
  const int tid = threadIdx.x;
  f16* Gb = Gh + (long)b * 1048576;
  const long pbase = ((long)b * 36 + tileid) * 16384;
#pragma unroll
  for (int it = 0; it < 16; ++it) {
    const int e = it * 1024 + tid * 4;
    const int r = e >> 7, c = e & 127;
    f16x4 p0 = *(const f16x4*)(part + pbase + e);
    f16x4 p1 = *(const f16x4*)(part + pbase + 2359296 + e);
    f16x4 p2 = *(const f16x4*)(part + pbase + 4718592 + e);
    f16x4 p3 = *(const f16x4*)(part + pbase + 7077888 + e);
    f16x4 sv;
#pragma unroll
    for (int j = 0; j < 4; ++j)
      sv[j] = (f16)((float)p0[j] + (float)p1[j] + (float)p2[j] + (float)p3[j]);
    *(f16x4*)(Gb + (long)(ti * 128 + r) * 1024 + tj * 128 + c) = sv;
    *(f16x4*)&tl[r][c] = sv;
  }
  if (ti != tj) {
    __syncthreads();
#pragma unroll
    for (int it = 0; it < 16; ++it) {
      const int e = it * 1024 + tid * 4;
      const int r = e >> 7, c = e & 127;
      f16x4 v;
      v[0] = tl[c + 0][r];
      v[1] = tl[c + 1][r];
      v[2] = tl[c + 2][r];
      v[3] = tl[c + 3][r];
      *(f16x4*)(Gb + (long)(tj * 128 + r) * 1024 + ti * 128 + c) = v;
    }
  }
}

extern "C" void kernel_launch(void* const* d_in, const int* in_sizes, int n_in,
                              void* d_out, int out_size, void* d_ws, size_t ws_size,
                              hipStream_t stream) {
  const float* x      = (const float*)d_in[0];
  const float* norm_w = (const float*)d_in[1];
  const float* norm_b = (const float*)d_in[2];
  const float* qkv_w  = (const float*)d_in[3];
  const float* qkv_b  = (const float*)d_in[4];
  const float* proj_w = (const float*)d_in[5];
  const float* proj_b = (const float*)d_in[6];
  float* out = (float*)d_out;
  char* ws = (char*)d_ws;

  const size_t OFF_H   = 0;
  const size_t OFF_HT  = 33554432;
  const size_t OFF_T1  = 33554432;        // alias (after G)
  const size_t OFF_T2  = 41943040;
  const size_t OFF_WH  = 67108864;
  const size_t OFF_PH  = 73400320;
  const size_t OFF_WQT = 75497472;
  const size_t OFF_GH  = 77594624;
  const size_t OFF_HS  = 85983232;
  const size_t OFF_U   = 85999616;
  const size_t OFF_W   = 86016000;
  const size_t OFF_C2  = 86032384;
  const size_t OFF_PART= 100663296;

  f16* H    = (f16*)(ws + OFF_H);
  f16* Ht   = (f16*)(ws + OFF_HT);
  f16* T1   = (f16*)(ws + OFF_T1);
  f16* T2   = (f16*)(ws + OFF_T2);
  f16* Wh   = (f16*)(ws + OFF_WH);
  f16* Ph   = (f16*)(ws + OFF_PH);
  f16* WqT  = (f16*)(ws + OFF_WQT);
  f16* Gh   = (f16*)(ws + OFF_GH);
  float* hs   = (float*)(ws + OFF_HS);
  float* uvec = (float*)(ws + OFF_U);
  float* wvec = (float*)(ws + OFF_W);
  float* c2v  = (float*)(ws + OFF_C2);
  f16* part = (f16*)(ws + OFF_PART);

  cast2_f32_f16<<<dim3(3072), 256, 0, stream>>>(qkv_w + 1048576, Wh + 1048576, 524288,
                                                proj_w, Ph, 262144);
  transcast_kernel<<<dim3(16, 16), 256, 0, stream>>>(qkv_w, WqT);

  ln_kernel<<<dim3(4096), 256, 0, stream>>>(x, norm_w, norm_b, H);

  hipMemsetAsync(ws + OFF_HS, 0, 16384, stream);
  transpose_cs_kernel<<<dim3(16, 64, 4), 256, 0, stream>>>(H, Ht, hs);
  gemv_uw<<<dim3(8192), 64, 0, stream>>>(Wh, hs, uvec, wvec);

  gemmGt<<<dim3(36, 1, 16), 256, 0, stream>>>(Ht, part);
  treduce<<<dim3(36, 4), 256, 0, stream>>>(part, Gh);

  // S1 = Wk (x) G  -> T1  (split-K=2)
  gemm128s<<<dim3(8, 8, 8), 256, 0, stream>>>(Wh + 1048576, Gh, 0L, 1048576L, part);
  reduce2<0><<<dim3(256, 4), 256, 0, stream>>>(part, T1, nullptr, nullptr, nullptr, nullptr);
  // M' = (S1 (x) Wv + rank-1 bias terms)/32 -> T2
  gemm128s<<<dim3(8, 8, 8), 256, 0, stream>>>(T1, Wh + 2097152, 1048576L, 0L, part);
  reduce2<1><<<dim3(256, 4), 256, 0, stream>>>(part, T2, uvec, wvec, qkv_b + 1024, qkv_b + 2048);
  // R = P (x) M' -> T1
  gemm128s<<<dim3(8, 8, 8), 256, 0, stream>>>(Ph, T2, 0L, 1048576L, part);
  reduce2<0><<<dim3(256, 4), 256, 0, stream>>>(part, T1, nullptr, nullptr, nullptr, nullptr);
  // W2T = R (x) Wq^T -> T2
  gemm128s<<<dim3(8, 8, 8), 256, 0, stream>>>(T1, WqT, 1048576L, 0L, part);
  reduce2<0><<<dim3(256, 4), 256, 0, stream>>>(part, T2, nullptr, nullptr, nullptr, nullptr);
  // c2 = R bq + proj_b
  c2_kernel<<<dim3(4096), 64, 0, stream>>>(T1, qkv_b, proj_b, c2v);
  // out = X + H (x) W2T + c2
  gemm256f<<<dim3(4, 64), 512, 0, stream>>>(H, T2, x, c2v, out);
}

// Round 8
// 235.266 us; speedup vs baseline: 1.0757x; 1.0757x over previous
//
#include <hip/hip_runtime.h>

typedef _Float16 f16;
typedef _Float16 f16x4 __attribute__((ext_vector_type(4)));
typedef _Float16 f16x8 __attribute__((ext_vector_type(8)));
typedef float f32x4 __attribute__((ext_vector_type(4)));

#define AS1 __attribute__((address_space(1)))
#define AS3 __attribute__((address_space(3)))

__device__ __forceinline__ void gl_lds16(const f16* g, f16* l) {
  __builtin_amdgcn_global_load_lds((const AS1 void*)g, (AS3 void*)l, 16, 0, 0);
}

// ---------------- LayerNorm: x (fp32) -> H (f16), one WAVE per row ----------------
__global__ __launch_bounds__(256) void ln_kernel(const float* __restrict__ x,
                                                 const float* __restrict__ gw,
                                                 const float* __restrict__ gb,
                                                 f16* __restrict__ H) {
  const int wv = threadIdx.x >> 6, lane = threadIdx.x & 63;
  const long row = (long)blockIdx.x * 4 + wv;
  const float* xr = x + row * 1024;
  float4 v[4];
  float s = 0.f, s2 = 0.f;
#pragma unroll
  for (int j = 0; j < 4; ++j) {
    v[j] = ((const float4*)xr)[lane + 64 * j];
    s  += v[j].x + v[j].y + v[j].z + v[j].w;
    s2 += v[j].x * v[j].x + v[j].y * v[j].y + v[j].z * v[j].z + v[j].w * v[j].w;
  }
#pragma unroll
  for (int off = 32; off > 0; off >>= 1) {
    s  += __shfl_xor(s, off);
    s2 += __shfl_xor(s2, off);
  }
  const float mu = s * (1.0f / 1024.0f);
  const float rstd = rsqrtf(s2 * (1.0f / 1024.0f) - mu * mu + 1e-5f);
#pragma unroll
  for (int j = 0; j < 4; ++j) {
    const float4 w4 = ((const float4*)gw)[lane + 64 * j];
    const float4 b4 = ((const float4*)gb)[lane + 64 * j];
    f16x4 h;
    h[0] = (f16)((v[j].x - mu) * rstd * w4.x + b4.x);
    h[1] = (f16)((v[j].y - mu) * rstd * w4.y + b4.y);
    h[2] = (f16)((v[j].z - mu) * rstd * w4.z + b4.z);
    h[3] = (f16)((v[j].w - mu) * rstd * w4.w + b4.w);
    *(f16x4*)(H + row * 1024 + (lane + 64 * j) * 4) = h;
  }
}

// ---------------- transpose H (b,t,c) -> Ht (b,c,t), 64x64 tiles, fused colsum ----------------
__global__ __launch_bounds__(256) void transpose_cs_kernel(const f16* __restrict__ H,
                                                           f16* __restrict__ Ht,
                                                           float* __restrict__ hs) {
  __shared__ f16 tile[64][68];
  __shared__ float csum[4][64];
  const int b = blockIdx.z;
  const long Hb  = (long)b * 4096 * 1024;
  const long Htb = (long)b * 1024 * 4096;
  const int t0 = blockIdx.y * 64, c0 = blockIdx.x * 64;
  const int tid = threadIdx.x;
  const int r = tid >> 2, g0 = tid & 3;
#pragma unroll
  for (int i = 0; i < 4; ++i) {
    const int g = g0 + i * 4;
    f16x4 v = *(const f16x4*)(H + Hb + (long)(t0 + r) * 1024 + c0 + g * 4);
    *(f16x4*)&tile[r][g * 4] = v;
  }
  __syncthreads();
  {
    const int cl = tid & 63, rg = tid >> 6;
    float s = 0.f;
#pragma unroll
    for (int rr = 0; rr < 16; ++rr) s += (float)tile[rg * 16 + rr][cl];
    csum[rg][cl] = s;
  }
#pragma unroll
  for (int i = 0; i < 4; ++i) {
    const int g = g0 + i * 4;
    f16x4 v;
    v[0] = tile[g * 4 + 0][r];
    v[1] = tile[g * 4 + 1][r];
    v[2] = tile[g * 4 + 2][r];
    v[3] = tile[g * 4 + 3][r];
    *(f16x4*)(Ht + Htb + (long)(c0 + r) * 4096 + t0 + g * 4) = v;
  }
  __syncthreads();
  if (tid < 64)
    atomicAdd(&hs[b * 1024 + c0 + tid],
              csum[0][tid] + csum[1][tid] + csum[2][tid] + csum[3][tid]);
}

// ---------------- cast fp32 -> f16, two ranges in one dispatch ----------------
__global__ __launch_bounds__(256) void cast2_f32_f16(const float* __restrict__ s1,
                                                     f16* __restrict__ d1, int n4_1,
                                                     const float* __restrict__ s2,
                                                     f16* __restrict__ d2, int n4_2) {
  int i = blockIdx.x * 256 + threadIdx.x;
  const float* src; f16* dst;
  if (i < n4_1) { src = s1; dst = d1; }
  else { i -= n4_1; if (i >= n4_2) return; src = s2; dst = d2; }
  float4 v = ((const float4*)src)[i];
  f16x4 h;
  h[0] = (f16)v.x; h[1] = (f16)v.y; h[2] = (f16)v.z; h[3] = (f16)v.w;
  ((f16x4*)dst)[i] = h;
}

// ---------------- transpose+cast Wq: WqT[d][i] = Wq[i][d] ----------------
__global__ __launch_bounds__(256) void transcast_kernel(const float* __restrict__ W,
                                                        f16* __restrict__ WT) {
  __shared__ f16 tile[64][68];
  const int r0 = blockIdx.y * 64, c0 = blockIdx.x * 64;
  const int tid = threadIdx.x;
  const int r = tid >> 2, g0 = tid & 3;
#pragma unroll
  for (int i = 0; i < 4; ++i) {
    const int g = g0 + i * 4;
    float4 v = *(const float4*)(W + (long)(r0 + r) * 1024 + c0 + g * 4);
    tile[r][g * 4 + 0] = (f16)v.x;
    tile[r][g * 4 + 1] = (f16)v.y;
    tile[r][g * 4 + 2] = (f16)v.z;
    tile[r][g * 4 + 3] = (f16)v.w;
  }
  __syncthreads();
#pragma unroll
  for (int i = 0; i < 4; ++i) {
    const int g = g0 + i * 4;
    f16x4 v;
    v[0] = tile[g * 4 + 0][r];
    v[1] = tile[g * 4 + 1][r];
    v[2] = tile[g * 4 + 2][r];
    v[3] = tile[g * 4 + 3][r];
    *(f16x4*)(WT + (long)(c0 + r) * 1024 + r0 + g * 4) = v;
  }
}

// ---------------- u[b] = Wk hs_b, w[b] = Wv hs_b ----------------
__global__ void gemv_uw(const f16* __restrict__ Wh, const float* __restrict__ hs,
                        float* __restrict__ uvec, float* __restrict__ wvec) {
  const int bid = blockIdx.x;
  const int b = bid >> 11;
  const int rem = bid & 2047;
  const int which = rem >> 10;
  const int i = rem & 1023;
  const f16* row = Wh + (long)(1024 + which * 1024 + i) * 1024;
  const float* h = hs + b * 1024;
  const int lane = threadIdx.x;
  float s = 0.f;
#pragma unroll
  for (int j = 0; j < 2; ++j) {
    const int d = (lane + 64 * j) * 8;
    f16x8 a = *(const f16x8*)(row + d);
    float4 h0 = *(const float4*)(h + d);
    float4 h1 = *(const float4*)(h + d + 4);
    s += (float)a[0] * h0.x + (float)a[1] * h0.y + (float)a[2] * h0.z + (float)a[3] * h0.w
       + (float)a[4] * h1.x + (float)a[5] * h1.y + (float)a[6] * h1.z + (float)a[7] * h1.w;
  }
#pragma unroll
  for (int off = 32; off > 0; off >>= 1) s += __shfl_down(s, off);
  if (lane == 0) { (which ? wvec : uvec)[b * 1024 + i] = s; }
}

// ---------------- c2[b][c] = sum_i R[b][c][i]*bq[i] + proj_b[c] ----------------
__global__ void c2_kernel(const f16* __restrict__ R, const float* __restrict__ qkv_b,
                          const float* __restrict__ proj_b, float* __restrict__ c2) {
  const int bid = blockIdx.x;
  const int b = bid >> 10, c = bid & 1023;
  const f16* row = R + (long)b * 1048576 + (long)c * 1024;
  const int lane = threadIdx.x;
  float s = 0.f;
#pragma unroll
  for (int j = 0; j < 4; ++j) {
    const int i0 = (lane + 64 * j) * 4;
    f16x4 rv = *(const f16x4*)(row + i0);
    float4 q = *(const float4*)(qkv_b + i0);
    s += (float)rv[0] * q.x + (float)rv[1] * q.y + (float)rv[2] * q.z + (float)rv[3] * q.w;
  }
#pragma unroll
  for (int off = 32; off > 0; off >>= 1) s += __shfl_down(s, off);
  if (lane == 0) c2[b * 1024 + c] = s + proj_b[c];
}

// ================= shared GEMM machinery (BK = 64) =================
// LDS tile [rows][64] f16, 128B/row; chunk swizzle: stored_chunk = logical_chunk ^ (row&7).
// Staging: thread writes LDS linearly; pre-swizzle the GLOBAL source chunk.
// srow = tid>>3 (row within stage slab), slc = (tid&7)^((tid>>3)&7) (logical chunk).
// Read: elem = row*64 + ((kk ^ (row&7))*8), row&7 == lr&7 for all fragments.

#define GP64_COMMON()                                        \
  const int tid = threadIdx.x;                               \
  const int wave = tid >> 6, lane = tid & 63;                \
  const int lr = lane & 15, lk = lane >> 4;                  \
  const int srow = tid >> 3;                                 \
  const int slc  = (tid & 7) ^ (srow & 7);                   \
  const int kc0 = ((lk) ^ (lr & 7)) * 8;                     \
  const int kc1 = ((4 + lk) ^ (lr & 7)) * 8;

// wait for stage t to have landed; 8 loads per stage
#define GEMM_WAIT8(NBUF_, r_)                                               \
  do {                                                                      \
    if constexpr (NBUF_ == 3) {                                             \
      if ((r_) >= 2)      asm volatile("s_waitcnt vmcnt(16)" ::: "memory"); \
      else if ((r_) == 1) asm volatile("s_waitcnt vmcnt(8)" ::: "memory");  \
      else                asm volatile("s_waitcnt vmcnt(0)" ::: "memory");  \
    } else {                                                                \
      if ((r_) >= 1)      asm volatile("s_waitcnt vmcnt(8)" ::: "memory");  \
      else                asm volatile("s_waitcnt vmcnt(0)" ::: "memory");  \
    }                                                                       \
  } while (0)

// compute one ks half (16 MFMA) for a 64x64 wave tile
#define COMP64_HALF(asb_, bsb_, kc_)                                             \
  do {                                                                           \
    const f16* asb = (asb_);                                                     \
    const f16* bsb = (bsb_);                                                     \
    f16x8 af[4], bf[4];                                                          \
    _Pragma("unroll")                                                            \
    for (int mi = 0; mi < 4; ++mi)                                               \
      af[mi] = *(const f16x8*)(asb + (wm * 64 + mi * 16 + lr) * 64 + (kc_));     \
    _Pragma("unroll")                                                            \
    for (int ni = 0; ni < 4; ++ni)                                               \
      bf[ni] = *(const f16x8*)(bsb + (wn * 64 + ni * 16 + lr) * 64 + (kc_));     \
    _Pragma("unroll")                                                            \
    for (int mi = 0; mi < 4; ++mi)                                               \
      _Pragma("unroll")                                                          \
      for (int ni = 0; ni < 4; ++ni)                                             \
        acc[mi][ni] = __builtin_amdgcn_mfma_f32_16x16x32_f16(af[mi], bf[ni],     \
                                                             acc[mi][ni], 0, 0, 0); \
  } while (0)

// ---------------- chain GEMM: 128x128 tile, BK=64, NBUF=3, fused epilogue ----------------
// C[m,n] = sum_k A[m,k]*B[n,k]. MODE 0: f16 store. MODE 1: rank-1 bias + /32, f16.
template <int MODE>
__global__ __launch_bounds__(256) void gemm128(
    const f16* __restrict__ A, const f16* __restrict__ B, int K,
    long sA, long sB, long sC,
    f16* __restrict__ Ch,
    const float* __restrict__ uvec, const float* __restrict__ wvec,
    const float* __restrict__ bkv, const float* __restrict__ bvv) {
  const int b = blockIdx.z;
  A += (long)b * sA;
  B += (long)b * sB;
  // XCD remap (gridDim.x==8, gridDim.y==8)
  const int nx = blockIdx.y & 7;
  const int ny = blockIdx.x;

  GP64_COMMON();
  const int wm = wave >> 1, wn = wave & 1;

  __shared__ __align__(16) f16 As[3][8192];
  __shared__ __align__(16) f16 Bs[3][8192];

  const long aoffs = (long)(ny * 128 + srow) * K + slc * 8;
  const long boffs = (long)(nx * 128 + srow) * K + slc * 8;

  f32x4 zero = {0.f, 0.f, 0.f, 0.f};
  f32x4 acc[4][4];
#pragma unroll
  for (int mi = 0; mi < 4; ++mi)
#pragma unroll
    for (int ni = 0; ni < 4; ++ni) acc[mi][ni] = zero;

#define STAGE(buf, kt)                                                         \
  do {                                                                         \
    f16* asb = &As[buf][0];                                                    \
    f16* bsb = &Bs[buf][0];                                                    \
    _Pragma("unroll")                                                          \
    for (int q = 0; q < 4; ++q) {                                              \
      gl_lds16(A + aoffs + (long)q * 32 * K + (kt) * 64, asb + q * 2048 + tid * 8); \
      gl_lds16(B + boffs + (long)q * 32 * K + (kt) * 64, bsb + q * 2048 + tid * 8); \
    }                                                                          \
  } while (0)

  const int nt = K >> 6;
  STAGE(0, 0);
  STAGE(1, 1);
  int cur = 0, stg = 2;
  for (int t = 0; t < nt; ++t) {
    if (t + 2 < nt) STAGE(stg, t + 2);
    GEMM_WAIT8(3, nt - 1 - t);
    asm volatile("s_barrier" ::: "memory");
    __builtin_amdgcn_s_setprio(1);
    COMP64_HALF(&As[cur][0], &Bs[cur][0], kc0);
    COMP64_HALF(&As[cur][0], &Bs[cur][0], kc1);
    __builtin_amdgcn_s_setprio(0);
    asm volatile("s_waitcnt lgkmcnt(0)" ::: "memory");
    asm volatile("s_barrier" ::: "memory");
    cur = (cur + 1 == 3) ? 0 : cur + 1;
    stg = (stg + 1 == 3) ? 0 : stg + 1;
  }
#undef STAGE

  const long cb = (long)b * sC;
  const int m0 = ny * 128 + wm * 64;
  const int n0 = nx * 128 + wn * 64;
#pragma unroll
  for (int mi = 0; mi < 4; ++mi)
#pragma unroll
    for (int ni = 0; ni < 4; ++ni)
#pragma unroll
      for (int j = 0; j < 4; ++j) {
        const int gm = m0 + mi * 16 + lk * 4 + j;
        const int gn = n0 + ni * 16 + lr;
        float val = acc[mi][ni][j];
        if constexpr (MODE == 0) {
          Ch[cb + (long)gm * 1024 + gn] = (f16)val;
        } else {
          const float uu = uvec[b * 1024 + gm];
          const float ww = wvec[b * 1024 + gn];
          const float bkm = bkv[gm];
          const float bvn = bvv[gn];
          val = (val + uu * bvn + bkm * ww + 4096.0f * bkm * bvn) * 0.03125f;
          Ch[cb + (long)gm * 1024 + gn] = (f16)val;
        }
      }
}

// ---------------- FINAL GEMM: 256x256 tile, 8 waves, BK=64, NBUF=2 ----------------
__global__ __launch_bounds__(512) void gemm256f(
    const f16* __restrict__ A,       // H flat [16384][1024]
    const f16* __restrict__ Bw,      // W2T [4][1024][1024]
    const float* __restrict__ resid,
    const float* __restrict__ c2v,
    float* __restrict__ outF) {
  const int lin = blockIdx.y * 4 + blockIdx.x;
  const int xcd = lin & 7, slot = lin >> 3;
  const int ny = xcd * 8 + (slot >> 2);          // 0..63  (M tile)
  const int nx = slot & 3;                       // 0..3   (N tile)
  const int bb = ny >> 4;

  GP64_COMMON();
  const int wm = wave >> 2, wn = wave & 3;       // 2 x 4 wave grid

  __shared__ __align__(16) f16 As[2][16384];
  __shared__ __align__(16) f16 Bs[2][16384];

  const f16* Ab = A + (long)ny * 262144;
  const f16* Bb = Bw + (long)bb * 1048576 + (long)nx * 262144;
  const long offs = (long)srow * 1024 + slc * 8;   // srow 0..63

  f32x4 zero = {0.f, 0.f, 0.f, 0.f};
  f32x4 acc[8][4];
#pragma unroll
  for (int mi = 0; mi < 8; ++mi)
#pragma unroll
    for (int ni = 0; ni < 4; ++ni) acc[mi][ni] = zero;

#define STAGE(buf, kt)                                                             \
  do {                                                                             \
    f16* asb = &As[buf][0];                                                        \
    f16* bsb = &Bs[buf][0];                                                        \
    _Pragma("unroll")                                                              \
    for (int q = 0; q < 4; ++q) {                                                  \
      gl_lds16(Ab + offs + (long)q * 65536 + (kt) * 64, asb + q * 4096 + tid * 8); \
      gl_lds16(Bb + offs + (long)q * 65536 + (kt) * 64, bsb + q * 4096 + tid * 8); \
    }                                                                              \
  } while (0)

  const int nt = 16;
  STAGE(0, 0);
  int cur = 0;
  for (int t = 0; t < nt; ++t) {
    if (t + 1 < nt) STAGE(cur ^ 1, t + 1);
    GEMM_WAIT8(2, nt - 1 - t);
    asm volatile("s_barrier" ::: "memory");
    __builtin_amdgcn_s_setprio(1);
#pragma unroll
    for (int ks = 0; ks < 2; ++ks) {
      const int kc = ks ? kc1 : kc0;
      const f16* asb = &As[cur][0];
      const f16* bsb = &Bs[cur][0];
      f16x8 af[8], bf[4];
#pragma unroll
      for (int mi = 0; mi < 8; ++mi)
        af[mi] = *(const f16x8*)(asb + (wm * 128 + mi * 16 + lr) * 64 + kc);
#pragma unroll
      for (int ni = 0; ni < 4; ++ni)
        bf[ni] = *(const f16x8*)(bsb + (wn * 64 + ni * 16 + lr) * 64 + kc);
#pragma unroll
      for (int mi = 0; mi < 8; ++mi)
#pragma unroll
        for (int ni = 0; ni < 4; ++ni)
          acc[mi][ni] = __builtin_amdgcn_mfma_f32_16x16x32_f16(af[mi], bf[ni],
                                                               acc[mi][ni], 0, 0, 0);
    }
    __builtin_amdgcn_s_setprio(0);
    asm volatile("s_waitcnt lgkmcnt(0)" ::: "memory");
    asm volatile("s_barrier" ::: "memory");
    cur ^= 1;
  }
#undef STAGE

  // -------- LDS-staged vectorized epilogue (reuses As) --------
  float* weps = ((float*)&As[0][0]) + wave * 1088;
  const int m0 = ny * 256 + wm * 128;
  const int n0 = nx * 256 + wn * 64;
  const int err = lane >> 3;
  const int ecc = (lane & 7) * 4;
  float4 cc2[2];
#pragma unroll
  for (int q = 0; q < 2; ++q)
    cc2[q] = *(const float4*)&c2v[bb * 1024 + n0 + ecc + 32 * q];

#pragma unroll
  for (int mi = 0; mi < 8; ++mi) {
#pragma unroll
    for (int ni = 0; ni < 4; ++ni)
#pragma unroll
      for (int j = 0; j < 4; ++j)
        weps[(lk * 4 + j) * 68 + ni * 16 + lr] = acc[mi][ni][j];
    asm volatile("s_waitcnt lgkmcnt(0)" ::: "memory");
#pragma unroll
    for (int h = 0; h < 2; ++h)
#pragma unroll
      for (int q = 0; q < 2; ++q) {
        const int rr = err + 8 * h;
        const int cc = ecc + 32 * q;
        float4 o = *(const float4*)&weps[rr * 68 + cc];
        const long gbase = (long)(m0 + mi * 16 + rr) * 1024 + n0 + cc;
        const float4 rv = *(const float4*)&resid[gbase];
        float4 ov;
        ov.x = o.x + rv.x + cc2[q].x;
        ov.y = o.y + rv.y + cc2[q].y;
        ov.z = o.z + rv.z + cc2[q].z;
        ov.w = o.w + rv.w + cc2[q].w;
        *(float4*)&outF[gbase] = ov;
      }
  }
}

// ---------------- G = H^T H, upper-triangle tiles, split-K=4, BK=64, NBUF=2 ----------------
__global__ __launch_bounds__(256) void gemmGt(const f16* __restrict__ Ht,
                                              f16* __restrict__ part) {
  const int z = blockIdx.z;
  const int b = z & 3, ks4 = z >> 2;
  int ti = 0, trem = blockIdx.x;
  while (trem >= 8 - ti) { trem -= 8 - ti; ++ti; }
  const int tj = ti + trem;
  const f16* Hb = Ht + (long)b * 4194304;

  GP64_COMMON();
  const int wm = wave >> 1, wn = wave & 1;

  __shared__ __align__(16) f16 As[2][8192];
  __shared__ __align__(16) f16 Bs[2][8192];

  const long kbase = (long)ks4 * 1024;
  const long aoffs = (long)(ti * 128 + srow) * 4096 + kbase + slc * 8;
  const long boffs = (long)(tj * 128 + srow) * 4096 + kbase + slc * 8;

  f32x4 zero = {0.f, 0.f, 0.f, 0.f};
  f32x4 acc[4][4];
#pragma unroll
  for (int mi = 0; mi < 4; ++mi)
#pragma unroll
    for (int ni = 0; ni < 4; ++ni) acc[mi][ni] = zero;

#define STAGE(buf, kt)                                                              \
  do {                                                                              \
    f16* asb = &As[buf][0];                                                         \
    f16* bsb = &Bs[buf][0];                                                         \
    _Pragma("unroll")                                                               \
    for (int q = 0; q < 4; ++q) {                                                   \
      gl_lds16(Hb + aoffs + (long)q * 131072 + (kt) * 64, asb + q * 2048 + tid * 8);\
      gl_lds16(Hb + boffs + (long)q * 131072 + (kt) * 64, bsb + q * 2048 + tid * 8);\
    }                                                                               \
  } while (0)

  const int nt = 16;
  STAGE(0, 0);
  int cur = 0;
  for (int t = 0; t < nt; ++t) {
    if (t + 1 < nt) STAGE(cur ^ 1, t + 1);
    GEMM_WAIT8(2, nt - 1 - t);
    asm volatile("s_barrier" ::: "memory");
    __builtin_amdgcn_s_setprio(1);
    COMP64_HALF(&As[cur][0], &Bs[cur][0], kc0);
    COMP64_HALF(&As[cur][0], &Bs[cur][0], kc1);
    __builtin_amdgcn_s_setprio(0);
    asm volatile("s_waitcnt lgkmcnt(0)" ::: "memory");
    asm volatile("s_barrier" ::: "memory");
    cur ^= 1;
  }
#undef STAGE

  f16* P = part + ((long)z * 36 + blockIdx.x) * 16384;
#pragma unroll
  for (int mi = 0; mi < 4; ++mi)
#pragma unroll
    for (int ni = 0; ni < 4; ++ni)
#pragma unroll
      for (int j = 0; j < 4; ++j) {
        const int gm = wm * 64 + mi * 16 + lk * 4 + j;
        const int gn = wn * 64 + ni * 16 + lr;
        P[gm * 128 + gn] = (f16)acc[mi][ni][j];
      }
}

// ---------------- reduce 4 K-slices of triangular G partials -> Gh, mirror off-diag ----------------
__global__ __launch_bounds__(256) void treduce(const f16* __restrict__ part,
                                               f16* __restrict__ Gh) {
  const int tileid = blockIdx.x, b = blockIdx.y;
  int ti = 0, trem = tileid;
  while (trem >= 8 - ti) { trem -= 8 - ti; ++ti; }
  const int tj = ti + trem;
  __shared__ f16 tl[128][132];
  const int tid = threadIdx.x;
  f16* Gb = Gh + (long)b * 1048576;
  const long pbase = ((long)b * 36 + tileid) * 16384;
#pragma unroll
  for (int it = 0; it < 16; ++it) {
    const int e = it * 1024 + tid * 4;
    const int r = e >> 7, c = e & 127;
    f16x4 p0 = *(const f16x4*)(part + pbase + e);
    f16x4 p1 = *(const f16x4*)(part + pbase + 2359296 + e);
    f16x4 p2 = *(const f16x4*)(part + pbase + 4718592 + e);
    f16x4 p3 = *(const f16x4*)(part + pbase + 7077888 + e);
    f16x4 sv;
#pragma unroll
    for (int j = 0; j < 4; ++j)
      sv[j] = (f16)((float)p0[j] + (float)p1[j] + (float)p2[j] + (float)p3[j]);
    *(f16x4*)(Gb + (long)(ti * 128 + r) * 1024 + tj * 128 + c) = sv;
    *(f16x4*)&tl[r][c] = sv;
  }
  if (ti != tj) {
    __syncthreads();
#pragma unroll
    for (int it = 0; it < 16; ++it) {
      const int e = it * 1024 + tid * 4;
      const int r = e >> 7, c = e & 127;
      f16x4 v;
      v[0] = tl[c + 0][r];
      v[1] = tl[c + 1][r];
      v[2] = tl[c + 2][r];
      v[3] = tl[c + 3][r];
      *(f16x4*)(Gb + (long)(tj * 128 + r) * 1024 + ti * 128 + c) = v;
    }
  }
}

extern "C" void kernel_launch(void* const* d_in, const int* in_sizes, int n_in,
                              void* d_out, int out_size, void* d_ws, size_t ws_size,
                              hipStream_t stream) {
  const float* x      = (const float*)d_in[0];
  const float* norm_w = (const float*)d_in[1];
  const float* norm_b = (const float*)d_in[2];
  const float* qkv_w  = (const float*)d_in[3];
  const float* qkv_b  = (const float*)d_in[4];
  const float* proj_b = (const float*)d_in[6];
  const float* proj_w = (const float*)d_in[5];
  float* out = (float*)d_out;
  char* ws = (char*)d_ws;

  const size_t OFF_H   = 0;
  const size_t OFF_HT  = 33554432;
  const size_t OFF_T1  = 33554432;        // alias (after G)
  const size_t OFF_T2  = 41943040;
  const size_t OFF_WH  = 67108864;
  const size_t OFF_PH  = 73400320;
  const size_t OFF_WQT = 75497472;
  const size_t OFF_GH  = 77594624;
  const size_t OFF_HS  = 85983232;
  const size_t OFF_U   = 85999616;
  const size_t OFF_W   = 86016000;
  const size_t OFF_C2  = 86032384;
  const size_t OFF_PART= 100663296;

  f16* H    = (f16*)(ws + OFF_H);
  f16* Ht   = (f16*)(ws + OFF_HT);
  f16* T1   = (f16*)(ws + OFF_T1);
  f16* T2   = (f16*)(ws + OFF_T2);
  f16* Wh   = (f16*)(ws + OFF_WH);
  f16* Ph   = (f16*)(ws + OFF_PH);
  f16* WqT  = (f16*)(ws + OFF_WQT);
  f16* Gh   = (f16*)(ws + OFF_GH);
  float* hs   = (float*)(ws + OFF_HS);
  float* uvec = (float*)(ws + OFF_U);
  float* wvec = (float*)(ws + OFF_W);
  float* c2v  = (float*)(ws + OFF_C2);
  f16* part = (f16*)(ws + OFF_PART);

  cast2_f32_f16<<<dim3(3072), 256, 0, stream>>>(qkv_w + 1048576, Wh + 1048576, 524288,
                                                proj_w, Ph, 262144);
  transcast_kernel<<<dim3(16, 16), 256, 0, stream>>>(qkv_w, WqT);

  ln_kernel<<<dim3(4096), 256, 0, stream>>>(x, norm_w, norm_b, H);

  hipMemsetAsync(ws + OFF_HS, 0, 16384, stream);
  transpose_cs_kernel<<<dim3(16, 64, 4), 256, 0, stream>>>(H, Ht, hs);
  gemv_uw<<<dim3(8192), 64, 0, stream>>>(Wh, hs, uvec, wvec);

  gemmGt<<<dim3(36, 1, 16), 256, 0, stream>>>(Ht, part);
  treduce<<<dim3(36, 4), 256, 0, stream>>>(part, Gh);

  // S1 = Wk (x) G  -> T1
  gemm128<0><<<dim3(8, 8, 4), 256, 0, stream>>>(Wh + 1048576, Gh, 1024, 0L, 1048576L, 1048576L,
      T1, nullptr, nullptr, nullptr, nullptr);
  // M' = (S1 (x) Wv + rank-1 bias terms)/32 -> T2
  gemm128<1><<<dim3(8, 8, 4), 256, 0, stream>>>(T1, Wh + 2097152, 1024, 1048576L, 0L, 1048576L,
      T2, uvec, wvec, qkv_b + 1024, qkv_b + 2048);
  // R = P (x) M' -> T1
  gemm128<0><<<dim3(8, 8, 4), 256, 0, stream>>>(Ph, T2, 1024, 0L, 1048576L, 1048576L,
      T1, nullptr, nullptr, nullptr, nullptr);
  // W2T = R (x) Wq^T -> T2
  gemm128<0><<<dim3(8, 8, 4), 256, 0, stream>>>(T1, WqT, 1024, 1048576L, 0L, 1048576L,
      T2, nullptr, nullptr, nullptr, nullptr);
  // c2 = R bq + proj_b
  c2_kernel<<<dim3(4096), 64, 0, stream>>>(T1, qkv_b, proj_b, c2v);
  // out = X + H (x) W2T + c2
  gemm256f<<<dim3(4, 64), 512, 0, stream>>>(H, T2, x, c2v, out);
}